// Round 10
// baseline (394.096 us; speedup 1.0000x reference)
//
#include <hip/hip_runtime.h>
#include <hip/hip_bf16.h>

typedef _Float16 f16x8 __attribute__((ext_vector_type(8)));
typedef float f32x4 __attribute__((ext_vector_type(4)));

__device__ __forceinline__ void gload_lds16(const void* gptr, void* lptr) {
  __builtin_amdgcn_global_load_lds(
      (const __attribute__((address_space(1))) void*)gptr,
      (__attribute__((address_space(3))) void*)lptr, 16, 0, 0);
}

// ---------------- K1a+K1c+y-zero merged ----------------
// blocks [0,2048): k_pre body (4 waves, one (b,i,j) site per wave)
// blocks [2048,2432): k_build_rt body
// blocks [2432,2944): zero y (replaces hipMemsetAsync dispatch)
__global__ __launch_bounds__(256) void k_prt(const float* __restrict__ x,
                                             const float* __restrict__ mask,
                                             _Float16* __restrict__ f_h,
                                             float* __restrict__ sumsq,
                                             float* __restrict__ mlow,
                                             _Float16* __restrict__ Rt,
                                             float* __restrict__ y) {
  if (blockIdx.x < 2048) {
    int wave = threadIdx.x >> 6, c = threadIdx.x & 63;
    int blk = blockIdx.x * 4 + wave;   // b*4096 + i*64 + j
    int b = blk >> 12, ij = blk & 4095;
    int i = ij >> 6, j = ij & 63;
    size_t base = ((size_t)(b * 128 + 2 * i) * 128 + 2 * j) * 64 + c;
    float f = 0.25f * (x[base] + x[base + 64] + x[base + 128 * 64] + x[base + 128 * 64 + 64]);
    f_h[(size_t)blk * 64 + c] = (_Float16)f;
    float fsq = f * f;
    for (int off = 32; off; off >>= 1) fsq += __shfl_down(fsq, off);
    if (c == 0) {
      sumsq[blk] = fsq;
      size_t mb = (size_t)(b * 128 + 2 * i) * 128 + 2 * j;
      mlow[blk] = 0.25f * (mask[mb] + mask[mb + 1] + mask[mb + 128] + mask[mb + 129]);
    }
    return;
  }
  if (blockIdx.x >= 2432) {
    int idx = blockIdx.x - 2432;       // [0,512): 2,097,152 floats / 512 = 1024 f32x4
    f32x4* Y4 = (f32x4*)y;
    f32x4 z = {0.f, 0.f, 0.f, 0.f};
#pragma unroll
    for (int k = 0; k < 4; ++k) Y4[idx * 1024 + k * 256 + threadIdx.x] = z;
    return;
  }
  int idx = blockIdx.x - 2048;          // [0,384) = 3 * 64 * 2
  int kh = idx % 3;
  int rest = idx / 3;
  int li = rest & 63, b = rest >> 6;
  int r = 2 * li + kh;
  __shared__ float xrow[128 * 65];
  if (r < 128) {
    for (int t = threadIdx.x; t < 8192; t += 256) {
      int v = t >> 6, c = t & 63;
      xrow[v * 65 + c] = x[((size_t)(b * 128 + r) * 128 + v) * 64 + c];
    }
  }
  __syncthreads();
  for (int id2 = threadIdx.x; id2 < 12288; id2 += 256) {
    int lj = id2 & 63, rest2 = id2 >> 6;
    int c = rest2 & 63, kw = rest2 >> 6;
    int v = 2 * lj + kw;
    float val = (r < 128 && v < 128) ? xrow[v * 65 + c] : 0.f;
    int n = (kh * 3 + kw) * 64 + c;
    Rt[((size_t)b * 640 + n) * 4096 + li * 64 + lj] = (_Float16)val;
  }
}

// ---------------- K1b+K1d merged: invn[l] + mm flags (LDS) + deterministic compaction --
__global__ __launch_bounds__(1024) void k_norm_compact(const float* __restrict__ sumsq,
                                                       const float* __restrict__ mlow,
                                                       float* __restrict__ invn,
                                                       int* __restrict__ actIdx,
                                                       int* __restrict__ nAct) {
  int b = blockIdx.x;
  int t = threadIdx.x;  // 1024
  __shared__ unsigned char mmf[4096];
  for (int l = t; l < 4096; l += 1024) {
    int li = l >> 6, lj = l & 63;
    float s = 0.f;
    bool ok = true;
    for (int dh = -1; dh <= 1; ++dh)
      for (int dw = -1; dw <= 1; ++dw) {
        int ii = li + dh, jj = lj + dw;
        float mv = 0.f;
        if ((unsigned)ii < 64u && (unsigned)jj < 64u) {
          int idx = (b << 12) + ii * 64 + jj;
          s += sumsq[idx];
          mv = mlow[idx];
        }
        ok = ok && (mv == 1.0f);   // exact-1.0 patch <=> all 9 entries exactly 1.0
      }
    invn[(b << 12) + l] = 1.0f / fmaxf(sqrtf(s), 1e-4f);
    mmf[l] = ok ? 1 : 0;
  }
  __syncthreads();
  int lane = t & 63, wv = t >> 6;  // 16 waves
  __shared__ int wsum[16];
  __shared__ int sbase;
  if (t == 0) sbase = 0;
  __syncthreads();
  for (int chunk = 0; chunk < 4; ++chunk) {
    int l = chunk * 1024 + t;
    int flag = mmf[l] ? 1 : 0;
    unsigned long long m = __ballot(flag);
    int wpre = __popcll(m & ((1ull << lane) - 1ull));
    if (lane == 0) wsum[wv] = __popcll(m);
    __syncthreads();
    int off = sbase;
    for (int w2 = 0; w2 < wv; ++w2) off += wsum[w2];
    if (flag) {
      int pos = off + wpre;
      if (pos < 1024) actIdx[(b << 10) + pos] = l;
    }
    __syncthreads();
    if (t == 0) {
      int s2 = 0;
      for (int w2 = 0; w2 < 16; ++w2) s2 += wsum[w2];
      sbase += s2;
    }
    __syncthreads();
  }
  int total = sbase;
  if (t >= total) actIdx[(b << 10) + t] = 0;  // safe index; weight will be 0
  if (t == 0) nAct[b] = (total > 1024) ? 1024 : total;
}

// ---------------- K1p+K1e merged (deps f_h / Rt+actIdx both ready) --------------------
// blocks [0,2048): build_p (4 waves/block); blocks [2048,3328): rtsub (8B packed stores)
__global__ __launch_bounds__(256) void k_psub(const _Float16* __restrict__ f_h,
                                              _Float16* __restrict__ P,
                                              const _Float16* __restrict__ Rt,
                                              const int* __restrict__ actIdx,
                                              _Float16* __restrict__ Rts) {
  if (blockIdx.x < 2048) {
    int wave = threadIdx.x >> 6, c = threadIdx.x & 63;
    int blk = blockIdx.x * 4 + wave;  // b*4096+l
    int b = blk >> 12, l = blk & 4095;
    int li = l >> 6, lj = l & 63;
    _Float16* dst = P + (size_t)blk * 576 + c;
#pragma unroll
    for (int kk = 0; kk < 9; ++kk) {
      int kh = kk / 3, kw = kk % 3;
      int ii = li + kh - 1, jj = lj + kw - 1;
      _Float16 v = (_Float16)0.f;
      if ((unsigned)ii < 64u && (unsigned)jj < 64u)
        v = f_h[((size_t)(b << 12) + ii * 64 + jj) * 64 + c];
      dst[kk * 64] = v;
    }
    return;
  }
  int idx = blockIdx.x - 2048;        // [0,1280) = 640 * 2
  int n = idx % 640, b = idx / 640;
  const unsigned short* src = (const unsigned short*)(Rt + ((size_t)b * 640 + n) * 4096);
  _Float16* dst = Rts + ((size_t)b * 640 + n) * 1024;
  const int* aIdx = actIdx + (b << 10);
  int s0 = threadIdx.x * 4;           // 256 threads x 4 = 1024 slots
  unsigned long long v = (unsigned long long)src[aIdx[s0]] |
                         ((unsigned long long)src[aIdx[s0 + 1]] << 16) |
                         ((unsigned long long)src[aIdx[s0 + 2]] << 32) |
                         ((unsigned long long)src[aIdx[s0 + 3]] << 48);
  *(unsigned long long*)(dst + s0) = v;
}

// ---------------- K2: symmetric GEMM, BK=64 + XOR slot-swizzle + XCD idx swizzle.
// att stores are nontemporal: fuse re-reads att from HBM regardless (measured FETCH
// ~142MB in fuse4), so caching the 134MB write is pure L2/L3 pollution. ---------------
__global__ __launch_bounds__(256) void k_gemm_sim(const _Float16* __restrict__ P,
                                                  const float* __restrict__ invn,
                                                  float* __restrict__ att) {
  int b = blockIdx.z;
  const _Float16* Ab = P + (size_t)b * 4096 * 576;
  int idx0 = blockIdx.x;              // 528 = 8 * 66, bijective XCD-contiguous swizzle
  int idx = (idx0 & 7) * 66 + (idx0 >> 3);
  int bj = (int)((sqrtf(8.f * (float)idx + 1.f) - 1.f) * 0.5f);
  while ((bj + 1) * (bj + 2) / 2 <= idx) ++bj;
  while (bj * (bj + 1) / 2 > idx) --bj;
  int bi = idx - bj * (bj + 1) / 2;
  int rowBase = bi * 128, colBase = bj * 128;
  bool diag = (bi == bj);

  __shared__ alignas(16) _Float16 As[128 * 64];
  __shared__ alignas(16) _Float16 Bs[128 * 64];
  __shared__ alignas(16) float tbuf[32][132];
  int tid = threadIdx.x, wave = tid >> 6, lane = tid & 63;
  int q = lane >> 4, rr = lane & 15;
  int wr = (wave >> 1) * 64, wc = (wave & 1) * 64;
  f32x4 acc[4][4] = {};
  for (int kt = 0; kt < 576; kt += 64) {
    __syncthreads();
#pragma unroll
    for (int t = 0; t < 4; ++t) {
      int chunk = t * 256 + wave * 64 + lane;  // 1024 chunks of 16B per tile
      int row = chunk >> 3;
      int kc = ((chunk & 7) ^ (row & 7)) * 8;  // pre-swizzled source slot
      gload_lds16(Ab + (size_t)(rowBase + row) * 576 + kt + kc,
                  As + (size_t)(t * 256 + wave * 64) * 8);
      if (!diag)
        gload_lds16(Ab + (size_t)(colBase + row) * 576 + kt + kc,
                    Bs + (size_t)(t * 256 + wave * 64) * 8);
    }
    __syncthreads();
    const _Float16* Bsrc = diag ? As : Bs;
#pragma unroll
    for (int ks = 0; ks < 2; ++ks) {
      f16x8 af[4], bf[4];
#pragma unroll
      for (int mi = 0; mi < 4; ++mi) {
        int r = wr + mi * 16 + rr;
        int ps = (ks * 4 + q) ^ (r & 7);
        af[mi] = *(const f16x8*)(As + r * 64 + ps * 8);
      }
#pragma unroll
      for (int ni = 0; ni < 4; ++ni) {
        int r = wc + ni * 16 + rr;
        int ps = (ks * 4 + q) ^ (r & 7);
        bf[ni] = *(const f16x8*)(Bsrc + r * 64 + ps * 8);
      }
#pragma unroll
      for (int mi = 0; mi < 4; ++mi)
#pragma unroll
        for (int ni = 0; ni < 4; ++ni)
          acc[mi][ni] = __builtin_amdgcn_mfma_f32_16x16x32_f16(af[mi], bf[ni], acc[mi][ni], 0, 0, 0);
    }
  }
  float* attb = att + ((size_t)b << 24);
#pragma unroll
  for (int ni = 0; ni < 4; ++ni) {
    int gc = colBase + wc + ni * 16 + rr;
    float sc = invn[(b << 12) + gc];
#pragma unroll
    for (int mi = 0; mi < 4; ++mi)
#pragma unroll
      for (int reg = 0; reg < 4; ++reg) {
        int gr = rowBase + wr + mi * 16 + q * 4 + reg;
        __builtin_nontemporal_store(acc[mi][ni][reg] * sc,
                                    attb + ((size_t)gr << 12) + gc);
      }
  }
  if (diag) return;
  const float* ivrow = invn + (b << 12) + rowBase;
#pragma unroll
  for (int ph = 0; ph < 4; ++ph) {
    __syncthreads();
    if ((ph >> 1) == (wc >> 6)) {
      int nlo = (ph & 1) * 2;
#pragma unroll
      for (int nn = 0; nn < 2; ++nn) {
        int ni = nlo + nn;
        int rloc = nn * 16 + rr;
#pragma unroll
        for (int mi = 0; mi < 4; ++mi)
          *(f32x4*)&tbuf[rloc][wr + mi * 16 + q * 4] = acc[mi][ni];
      }
    }
    __syncthreads();
    int r = tid >> 3;
    int cbase = (tid & 7) * 16;
    int grow = colBase + ph * 32 + r;
    float* dst = attb + ((size_t)grow << 12) + rowBase + cbase;
#pragma unroll
    for (int cc = 0; cc < 16; cc += 4) {
      f32x4 v = *(f32x4*)&tbuf[r][cbase + cc];
      f32x4 s = *(const f32x4*)(ivrow + cbase + cc);
      __builtin_nontemporal_store(v * s, (f32x4*)(dst + cc));
    }
  }
}

// ---------------- K3: fuse (9-pt diagonal stencil) + masked softmax, active cols only.
// 8192 blocks, one p each (max TLP — measured optimum; fuse5/fuse6 reuse variants both
// regressed: the kernel is latency-bound, not traffic-bound). --------------------------
__global__ __launch_bounds__(256) void k_fuse_softmax3(const float* __restrict__ att,
                                                       const int* __restrict__ actIdx,
                                                       const int* __restrict__ nAct,
                                                       _Float16* __restrict__ Asub) {
  int blk0 = blockIdx.x;                    // XCD-contiguous swizzle: 8192 = 8 * 1024
  int blk = (blk0 & 7) * 1024 + (blk0 >> 3);
  int b = blk >> 12, p = blk & 4095;
  const float* Y = att + ((size_t)b << 24);
  const int* aIdx = actIdx + (b << 10);
  int na = nAct[b];
  int tid = threadIdx.x;
  int pi = p >> 6, pj = p & 63;
  int acol = pj * 64 + pi;                  // col-major flat index of p

  int ls[4];
  bool act[4];
  float F[4] = {0.f, 0.f, 0.f, 0.f};
#pragma unroll
  for (int s4 = 0; s4 < 4; ++s4) {
    int slot = s4 * 256 + tid;
    ls[s4] = aIdx[slot];                    // safe 0 for padded slots
    act[s4] = (slot < na);
  }

#pragma unroll
  for (int d2 = -1; d2 <= 1; ++d2) {
    int a2 = acol + d2;
    if ((unsigned)a2 >= 4096u) continue;    // wave-uniform branch
    int p2 = ((a2 & 63) << 6) | (a2 >> 6);
    int l2[4];
    bool lok[4];
#pragma unroll
    for (int s4 = 0; s4 < 4; ++s4) {
      int l = ls[s4];
      int bcol = ((l & 63) << 6) | (l >> 6);
      int b2 = bcol + d2;
      lok[s4] = act[s4] && ((unsigned)b2 < 4096u);
      int b2c = lok[s4] ? b2 : 0;
      l2[s4] = ((b2c & 63) << 6) | (b2c >> 6);  // consecutive across lanes in active runs
    }
#pragma unroll
    for (int d1 = -1; d1 <= 1; ++d1) {
      int qq = p2 + d1;
      if ((unsigned)qq >= 4096u) continue;  // wave-uniform branch
      const float* row = Y + ((size_t)qq << 12);
#pragma unroll
      for (int s4 = 0; s4 < 4; ++s4) {
        int rr2 = l2[s4] + d1;
        if (lok[s4] && (unsigned)rr2 < 4096u) F[s4] += row[rr2];
      }
    }
  }

  float z[4];
  float mx = (na < 4096) ? 0.f : -1e30f;    // masked columns contribute logit 0
#pragma unroll
  for (int s4 = 0; s4 < 4; ++s4) {
    z[s4] = act[s4] ? F[s4] * 10.f : -1e30f;
    mx = fmaxf(mx, z[s4]);
  }
  __shared__ float red[4];
  for (int off = 32; off; off >>= 1) mx = fmaxf(mx, __shfl_down(mx, off));
  if ((tid & 63) == 0) red[tid >> 6] = mx;
  __syncthreads();
  mx = fmaxf(fmaxf(red[0], red[1]), fmaxf(red[2], red[3]));
  float e[4];
  float esum = 0.f;
#pragma unroll
  for (int s4 = 0; s4 < 4; ++s4) {
    e[s4] = act[s4] ? __expf(z[s4] - mx) : 0.f;
    esum += e[s4];
  }
  for (int off = 32; off; off >>= 1) esum += __shfl_down(esum, off);
  __syncthreads();
  if ((tid & 63) == 0) red[tid >> 6] = esum;
  __syncthreads();
  float total = red[0] + red[1] + red[2] + red[3] + (float)(4096 - na) * __expf(0.f - mx);
  float inv = 1.f / total;
  _Float16* Ap = Asub + ((size_t)blk << 10);
#pragma unroll
  for (int s4 = 0; s4 < 4; ++s4) Ap[s4 * 256 + tid] = (_Float16)(e[s4] * inv);
}

// ---------------- K4: G = Asub * Rts^T, BK=64 + swizzle, K trimmed to ceil(na/64)*64.
// Slots >= na have Asub exactly 0 (e=0 stored), so skipped MFMA contribute +0 exactly:
// bit-identical acc. Atomic scatter into y. --------------------------------------------
__global__ __launch_bounds__(256) void k_gemm_recon(const _Float16* __restrict__ Asub,
                                                    const _Float16* __restrict__ Rts,
                                                    const int* __restrict__ nAct,
                                                    float* __restrict__ y) {
  int b = blockIdx.z;
  const _Float16* Ab = Asub + ((size_t)b << 22);
  const _Float16* Bb = Rts + (size_t)b * 640 * 1024;
  int kMax = ((nAct[b] + 63) >> 6) << 6;
  int rowBase = blockIdx.y * 128, colBase = blockIdx.x * 128;  // col over 640
  __shared__ alignas(16) _Float16 As[128 * 64];
  __shared__ alignas(16) _Float16 Bs[128 * 64];
  int tid = threadIdx.x, wave = tid >> 6, lane = tid & 63;
  int q = lane >> 4, rr = lane & 15;
  int wr = (wave >> 1) * 64, wc = (wave & 1) * 64;
  f32x4 acc[4][4] = {};
  for (int kt = 0; kt < kMax; kt += 64) {
    __syncthreads();
#pragma unroll
    for (int t = 0; t < 4; ++t) {
      int chunk = t * 256 + wave * 64 + lane;
      int row = chunk >> 3;
      int kc = ((chunk & 7) ^ (row & 7)) * 8;
      gload_lds16(Ab + ((size_t)(rowBase + row) << 10) + kt + kc,
                  As + (size_t)(t * 256 + wave * 64) * 8);
      gload_lds16(Bb + ((size_t)(colBase + row) << 10) + kt + kc,
                  Bs + (size_t)(t * 256 + wave * 64) * 8);
    }
    __syncthreads();
#pragma unroll
    for (int ks = 0; ks < 2; ++ks) {
      f16x8 af[4], bf[4];
#pragma unroll
      for (int mi = 0; mi < 4; ++mi) {
        int r = wr + mi * 16 + rr;
        int ps = (ks * 4 + q) ^ (r & 7);
        af[mi] = *(const f16x8*)(As + r * 64 + ps * 8);
      }
#pragma unroll
      for (int ni = 0; ni < 4; ++ni) {
        int r = wc + ni * 16 + rr;
        int ps = (ks * 4 + q) ^ (r & 7);
        bf[ni] = *(const f16x8*)(Bs + r * 64 + ps * 8);
      }
#pragma unroll
      for (int mi = 0; mi < 4; ++mi)
#pragma unroll
        for (int ni = 0; ni < 4; ++ni)
          acc[mi][ni] = __builtin_amdgcn_mfma_f32_16x16x32_f16(af[mi], bf[ni], acc[mi][ni], 0, 0, 0);
    }
  }
#pragma unroll
  for (int ni = 0; ni < 4; ++ni) {
    int gc = colBase + wc + ni * 16 + rr;
    if (gc < 576) {
      int kk = gc >> 6, c = gc & 63;
      int kh = kk / 3, kw = kk - kh * 3;
#pragma unroll
      for (int mi = 0; mi < 4; ++mi)
#pragma unroll
        for (int reg = 0; reg < 4; ++reg) {
          int gp = rowBase + wr + mi * 16 + q * 4 + reg;
          int i = gp >> 6, j = gp & 63;
          int u = 2 * i + kh, v = 2 * j + kw;
          if (u < 128 && v < 128)
            atomicAdd(y + (((size_t)((b * 128 + u) * 128 + v)) << 6) + c,
                      0.25f * acc[mi][ni][reg]);
        }
    }
  }
}

extern "C" void kernel_launch(void* const* d_in, const int* in_sizes, int n_in,
                              void* d_out, int out_size, void* d_ws, size_t ws_size,
                              hipStream_t stream) {
  const float* x = (const float*)d_in[0];
  const float* mask = (const float*)d_in[1];
  float* out = (float*)d_out;
  float* y = out;                 // [2][128][128][64]
  float* att = out + 2097152;     // [2][4096][4096]

  char* ws = (char*)d_ws;
  _Float16* f_h = (_Float16*)(ws + 0);            //  1,048,576 B
  float* sumsq = (float*)(ws + 0x100000);         //     32,768
  float* mlow = (float*)(ws + 0x108000);          //     32,768
  float* invn = (float*)(ws + 0x110000);          //     32,768
  _Float16* P = (_Float16*)(ws + 0x120000);       //  9,437,184
  _Float16* Rt = (_Float16*)(ws + 0xA20000);      // 10,485,760  [2][640][4096]
  int* actIdx = (int*)(ws + 0x1420000);           //      8,192  [2][1024]
  int* nAct = (int*)(ws + 0x1422000);             //          8
  _Float16* Rts = (_Float16*)(ws + 0x1430000);    //  2,621,440  [2][640][1024]
  _Float16* Asub = (_Float16*)(ws + 0x16B0000);   // 16,777,216  [2][4096][1024]
  (void)in_sizes; (void)n_in; (void)out_size; (void)ws_size;

  k_prt<<<2944, 256, 0, stream>>>(x, mask, f_h, sumsq, mlow, Rt, y);
  k_norm_compact<<<2, 1024, 0, stream>>>(sumsq, mlow, invn, actIdx, nAct);
  k_psub<<<3328, 256, 0, stream>>>(f_h, P, Rt, actIdx, Rts);
  k_gemm_sim<<<dim3(528, 1, 2), 256, 0, stream>>>(P, invn, att);
  k_fuse_softmax3<<<8192, 256, 0, stream>>>(att, actIdx, nAct, Asub);
  k_gemm_recon<<<dim3(5, 32, 2), 256, 0, stream>>>(Asub, Rts, nAct, y);
}

// Round 11
// 294.017 us; speedup vs baseline: 1.3404x; 1.3404x over previous
//
#include <hip/hip_runtime.h>
#include <hip/hip_bf16.h>

typedef _Float16 f16x8 __attribute__((ext_vector_type(8)));
typedef float f32x4 __attribute__((ext_vector_type(4)));

__device__ __forceinline__ void gload_lds16(const void* gptr, void* lptr) {
  __builtin_amdgcn_global_load_lds(
      (const __attribute__((address_space(1))) void*)gptr,
      (__attribute__((address_space(3))) void*)lptr, 16, 0, 0);
}

// ---------------- K1a+K1c+y-zero merged ----------------
// blocks [0,2048): k_pre body (4 waves, one (b,i,j) site per wave)
// blocks [2048,2432): k_build_rt body
// blocks [2432,2944): zero y (replaces hipMemsetAsync dispatch)
__global__ __launch_bounds__(256) void k_prt(const float* __restrict__ x,
                                             const float* __restrict__ mask,
                                             _Float16* __restrict__ f_h,
                                             float* __restrict__ sumsq,
                                             float* __restrict__ mlow,
                                             _Float16* __restrict__ Rt,
                                             float* __restrict__ y) {
  if (blockIdx.x < 2048) {
    int wave = threadIdx.x >> 6, c = threadIdx.x & 63;
    int blk = blockIdx.x * 4 + wave;   // b*4096 + i*64 + j
    int b = blk >> 12, ij = blk & 4095;
    int i = ij >> 6, j = ij & 63;
    size_t base = ((size_t)(b * 128 + 2 * i) * 128 + 2 * j) * 64 + c;
    float f = 0.25f * (x[base] + x[base + 64] + x[base + 128 * 64] + x[base + 128 * 64 + 64]);
    f_h[(size_t)blk * 64 + c] = (_Float16)f;
    float fsq = f * f;
    for (int off = 32; off; off >>= 1) fsq += __shfl_down(fsq, off);
    if (c == 0) {
      sumsq[blk] = fsq;
      size_t mb = (size_t)(b * 128 + 2 * i) * 128 + 2 * j;
      mlow[blk] = 0.25f * (mask[mb] + mask[mb + 1] + mask[mb + 128] + mask[mb + 129]);
    }
    return;
  }
  if (blockIdx.x >= 2432) {
    int idx = blockIdx.x - 2432;       // [0,512): 2,097,152 floats / 512 = 1024 f32x4
    f32x4* Y4 = (f32x4*)y;
    f32x4 z = {0.f, 0.f, 0.f, 0.f};
#pragma unroll
    for (int k = 0; k < 4; ++k) Y4[idx * 1024 + k * 256 + threadIdx.x] = z;
    return;
  }
  int idx = blockIdx.x - 2048;          // [0,384) = 3 * 64 * 2
  int kh = idx % 3;
  int rest = idx / 3;
  int li = rest & 63, b = rest >> 6;
  int r = 2 * li + kh;
  __shared__ float xrow[128 * 65];
  if (r < 128) {
    for (int t = threadIdx.x; t < 8192; t += 256) {
      int v = t >> 6, c = t & 63;
      xrow[v * 65 + c] = x[((size_t)(b * 128 + r) * 128 + v) * 64 + c];
    }
  }
  __syncthreads();
  for (int id2 = threadIdx.x; id2 < 12288; id2 += 256) {
    int lj = id2 & 63, rest2 = id2 >> 6;
    int c = rest2 & 63, kw = rest2 >> 6;
    int v = 2 * lj + kw;
    float val = (r < 128 && v < 128) ? xrow[v * 65 + c] : 0.f;
    int n = (kh * 3 + kw) * 64 + c;
    Rt[((size_t)b * 640 + n) * 4096 + li * 64 + lj] = (_Float16)val;
  }
}

// ---------------- K1b+K1d merged: invn[l] + mm flags (LDS) + deterministic compaction --
__global__ __launch_bounds__(1024) void k_norm_compact(const float* __restrict__ sumsq,
                                                       const float* __restrict__ mlow,
                                                       float* __restrict__ invn,
                                                       int* __restrict__ actIdx,
                                                       int* __restrict__ nAct) {
  int b = blockIdx.x;
  int t = threadIdx.x;  // 1024
  __shared__ unsigned char mmf[4096];
  for (int l = t; l < 4096; l += 1024) {
    int li = l >> 6, lj = l & 63;
    float s = 0.f;
    bool ok = true;
    for (int dh = -1; dh <= 1; ++dh)
      for (int dw = -1; dw <= 1; ++dw) {
        int ii = li + dh, jj = lj + dw;
        float mv = 0.f;
        if ((unsigned)ii < 64u && (unsigned)jj < 64u) {
          int idx = (b << 12) + ii * 64 + jj;
          s += sumsq[idx];
          mv = mlow[idx];
        }
        ok = ok && (mv == 1.0f);   // exact-1.0 patch <=> all 9 entries exactly 1.0
      }
    invn[(b << 12) + l] = 1.0f / fmaxf(sqrtf(s), 1e-4f);
    mmf[l] = ok ? 1 : 0;
  }
  __syncthreads();
  int lane = t & 63, wv = t >> 6;  // 16 waves
  __shared__ int wsum[16];
  __shared__ int sbase;
  if (t == 0) sbase = 0;
  __syncthreads();
  for (int chunk = 0; chunk < 4; ++chunk) {
    int l = chunk * 1024 + t;
    int flag = mmf[l] ? 1 : 0;
    unsigned long long m = __ballot(flag);
    int wpre = __popcll(m & ((1ull << lane) - 1ull));
    if (lane == 0) wsum[wv] = __popcll(m);
    __syncthreads();
    int off = sbase;
    for (int w2 = 0; w2 < wv; ++w2) off += wsum[w2];
    if (flag) {
      int pos = off + wpre;
      if (pos < 1024) actIdx[(b << 10) + pos] = l;
    }
    __syncthreads();
    if (t == 0) {
      int s2 = 0;
      for (int w2 = 0; w2 < 16; ++w2) s2 += wsum[w2];
      sbase += s2;
    }
    __syncthreads();
  }
  int total = sbase;
  if (t >= total) actIdx[(b << 10) + t] = 0;  // safe index; weight will be 0
  if (t == 0) nAct[b] = (total > 1024) ? 1024 : total;
}

// ---------------- K1p+K1e merged (deps f_h / Rt+actIdx both ready) --------------------
// blocks [0,2048): build_p (4 waves/block); blocks [2048,3328): rtsub (8B packed stores)
__global__ __launch_bounds__(256) void k_psub(const _Float16* __restrict__ f_h,
                                              _Float16* __restrict__ P,
                                              const _Float16* __restrict__ Rt,
                                              const int* __restrict__ actIdx,
                                              _Float16* __restrict__ Rts) {
  if (blockIdx.x < 2048) {
    int wave = threadIdx.x >> 6, c = threadIdx.x & 63;
    int blk = blockIdx.x * 4 + wave;  // b*4096+l
    int b = blk >> 12, l = blk & 4095;
    int li = l >> 6, lj = l & 63;
    _Float16* dst = P + (size_t)blk * 576 + c;
#pragma unroll
    for (int kk = 0; kk < 9; ++kk) {
      int kh = kk / 3, kw = kk % 3;
      int ii = li + kh - 1, jj = lj + kw - 1;
      _Float16 v = (_Float16)0.f;
      if ((unsigned)ii < 64u && (unsigned)jj < 64u)
        v = f_h[((size_t)(b << 12) + ii * 64 + jj) * 64 + c];
      dst[kk * 64] = v;
    }
    return;
  }
  int idx = blockIdx.x - 2048;        // [0,1280) = 640 * 2
  int n = idx % 640, b = idx / 640;
  const unsigned short* src = (const unsigned short*)(Rt + ((size_t)b * 640 + n) * 4096);
  _Float16* dst = Rts + ((size_t)b * 640 + n) * 1024;
  const int* aIdx = actIdx + (b << 10);
  int s0 = threadIdx.x * 4;           // 256 threads x 4 = 1024 slots
  unsigned long long v = (unsigned long long)src[aIdx[s0]] |
                         ((unsigned long long)src[aIdx[s0 + 1]] << 16) |
                         ((unsigned long long)src[aIdx[s0 + 2]] << 32) |
                         ((unsigned long long)src[aIdx[s0 + 3]] << 48);
  *(unsigned long long*)(dst + s0) = v;
}

// ---------------- K2: symmetric GEMM, BK=64 + XOR slot-swizzle + XCD idx swizzle.
// Plain (cache-combined) stores: R10 proved nontemporal att stores cause ~1.7x HBM
// write amplification (WRITE_SIZE 230MB vs 134MB logical) — L2 is the write combiner. --
__global__ __launch_bounds__(256) void k_gemm_sim(const _Float16* __restrict__ P,
                                                  const float* __restrict__ invn,
                                                  float* __restrict__ att) {
  int b = blockIdx.z;
  const _Float16* Ab = P + (size_t)b * 4096 * 576;
  int idx0 = blockIdx.x;              // 528 = 8 * 66, bijective XCD-contiguous swizzle
  int idx = (idx0 & 7) * 66 + (idx0 >> 3);
  int bj = (int)((sqrtf(8.f * (float)idx + 1.f) - 1.f) * 0.5f);
  while ((bj + 1) * (bj + 2) / 2 <= idx) ++bj;
  while (bj * (bj + 1) / 2 > idx) --bj;
  int bi = idx - bj * (bj + 1) / 2;
  int rowBase = bi * 128, colBase = bj * 128;
  bool diag = (bi == bj);

  __shared__ alignas(16) _Float16 As[128 * 64];
  __shared__ alignas(16) _Float16 Bs[128 * 64];
  __shared__ alignas(16) float tbuf[32][132];
  int tid = threadIdx.x, wave = tid >> 6, lane = tid & 63;
  int q = lane >> 4, rr = lane & 15;
  int wr = (wave >> 1) * 64, wc = (wave & 1) * 64;
  f32x4 acc[4][4] = {};
  for (int kt = 0; kt < 576; kt += 64) {
    __syncthreads();
#pragma unroll
    for (int t = 0; t < 4; ++t) {
      int chunk = t * 256 + wave * 64 + lane;  // 1024 chunks of 16B per tile
      int row = chunk >> 3;
      int kc = ((chunk & 7) ^ (row & 7)) * 8;  // pre-swizzled source slot
      gload_lds16(Ab + (size_t)(rowBase + row) * 576 + kt + kc,
                  As + (size_t)(t * 256 + wave * 64) * 8);
      if (!diag)
        gload_lds16(Ab + (size_t)(colBase + row) * 576 + kt + kc,
                    Bs + (size_t)(t * 256 + wave * 64) * 8);
    }
    __syncthreads();
    const _Float16* Bsrc = diag ? As : Bs;
#pragma unroll
    for (int ks = 0; ks < 2; ++ks) {
      f16x8 af[4], bf[4];
#pragma unroll
      for (int mi = 0; mi < 4; ++mi) {
        int r = wr + mi * 16 + rr;
        int ps = (ks * 4 + q) ^ (r & 7);
        af[mi] = *(const f16x8*)(As + r * 64 + ps * 8);
      }
#pragma unroll
      for (int ni = 0; ni < 4; ++ni) {
        int r = wc + ni * 16 + rr;
        int ps = (ks * 4 + q) ^ (r & 7);
        bf[ni] = *(const f16x8*)(Bsrc + r * 64 + ps * 8);
      }
#pragma unroll
      for (int mi = 0; mi < 4; ++mi)
#pragma unroll
        for (int ni = 0; ni < 4; ++ni)
          acc[mi][ni] = __builtin_amdgcn_mfma_f32_16x16x32_f16(af[mi], bf[ni], acc[mi][ni], 0, 0, 0);
    }
  }
  float* attb = att + ((size_t)b << 24);
#pragma unroll
  for (int ni = 0; ni < 4; ++ni) {
    int gc = colBase + wc + ni * 16 + rr;
    float sc = invn[(b << 12) + gc];
#pragma unroll
    for (int mi = 0; mi < 4; ++mi)
#pragma unroll
      for (int reg = 0; reg < 4; ++reg) {
        int gr = rowBase + wr + mi * 16 + q * 4 + reg;
        attb[((size_t)gr << 12) + gc] = acc[mi][ni][reg] * sc;
      }
  }
  if (diag) return;
  const float* ivrow = invn + (b << 12) + rowBase;
#pragma unroll
  for (int ph = 0; ph < 4; ++ph) {
    __syncthreads();
    if ((ph >> 1) == (wc >> 6)) {
      int nlo = (ph & 1) * 2;
#pragma unroll
      for (int nn = 0; nn < 2; ++nn) {
        int ni = nlo + nn;
        int rloc = nn * 16 + rr;
#pragma unroll
        for (int mi = 0; mi < 4; ++mi)
          *(f32x4*)&tbuf[rloc][wr + mi * 16 + q * 4] = acc[mi][ni];
      }
    }
    __syncthreads();
    int r = tid >> 3;
    int cbase = (tid & 7) * 16;
    int grow = colBase + ph * 32 + r;
    float* dst = attb + ((size_t)grow << 12) + rowBase + cbase;
#pragma unroll
    for (int cc = 0; cc < 16; cc += 4) {
      f32x4 v = *(f32x4*)&tbuf[r][cbase + cc];
      f32x4 s = *(const f32x4*)(ivrow + cbase + cc);
      *(f32x4*)(dst + cc) = v * s;
    }
  }
}

// ---------------- K3: fuse (9-pt diagonal stencil) + masked softmax, active cols only.
// 8192 blocks, one p each (max TLP — measured optimum; fuse5/fuse6 reuse variants both
// regressed: the kernel is latency-bound, not traffic-bound). --------------------------
__global__ __launch_bounds__(256) void k_fuse_softmax3(const float* __restrict__ att,
                                                       const int* __restrict__ actIdx,
                                                       const int* __restrict__ nAct,
                                                       _Float16* __restrict__ Asub) {
  int blk0 = blockIdx.x;                    // XCD-contiguous swizzle: 8192 = 8 * 1024
  int blk = (blk0 & 7) * 1024 + (blk0 >> 3);
  int b = blk >> 12, p = blk & 4095;
  const float* Y = att + ((size_t)b << 24);
  const int* aIdx = actIdx + (b << 10);
  int na = nAct[b];
  int tid = threadIdx.x;
  int pi = p >> 6, pj = p & 63;
  int acol = pj * 64 + pi;                  // col-major flat index of p

  int ls[4];
  bool act[4];
  float F[4] = {0.f, 0.f, 0.f, 0.f};
#pragma unroll
  for (int s4 = 0; s4 < 4; ++s4) {
    int slot = s4 * 256 + tid;
    ls[s4] = aIdx[slot];                    // safe 0 for padded slots
    act[s4] = (slot < na);
  }

#pragma unroll
  for (int d2 = -1; d2 <= 1; ++d2) {
    int a2 = acol + d2;
    if ((unsigned)a2 >= 4096u) continue;    // wave-uniform branch
    int p2 = ((a2 & 63) << 6) | (a2 >> 6);
    int l2[4];
    bool lok[4];
#pragma unroll
    for (int s4 = 0; s4 < 4; ++s4) {
      int l = ls[s4];
      int bcol = ((l & 63) << 6) | (l >> 6);
      int b2 = bcol + d2;
      lok[s4] = act[s4] && ((unsigned)b2 < 4096u);
      int b2c = lok[s4] ? b2 : 0;
      l2[s4] = ((b2c & 63) << 6) | (b2c >> 6);  // consecutive across lanes in active runs
    }
#pragma unroll
    for (int d1 = -1; d1 <= 1; ++d1) {
      int qq = p2 + d1;
      if ((unsigned)qq >= 4096u) continue;  // wave-uniform branch
      const float* row = Y + ((size_t)qq << 12);
#pragma unroll
      for (int s4 = 0; s4 < 4; ++s4) {
        int rr2 = l2[s4] + d1;
        if (lok[s4] && (unsigned)rr2 < 4096u) F[s4] += row[rr2];
      }
    }
  }

  float z[4];
  float mx = (na < 4096) ? 0.f : -1e30f;    // masked columns contribute logit 0
#pragma unroll
  for (int s4 = 0; s4 < 4; ++s4) {
    z[s4] = act[s4] ? F[s4] * 10.f : -1e30f;
    mx = fmaxf(mx, z[s4]);
  }
  __shared__ float red[4];
  for (int off = 32; off; off >>= 1) mx = fmaxf(mx, __shfl_down(mx, off));
  if ((tid & 63) == 0) red[tid >> 6] = mx;
  __syncthreads();
  mx = fmaxf(fmaxf(red[0], red[1]), fmaxf(red[2], red[3]));
  float e[4];
  float esum = 0.f;
#pragma unroll
  for (int s4 = 0; s4 < 4; ++s4) {
    e[s4] = act[s4] ? __expf(z[s4] - mx) : 0.f;
    esum += e[s4];
  }
  for (int off = 32; off; off >>= 1) esum += __shfl_down(esum, off);
  __syncthreads();
  if ((tid & 63) == 0) red[tid >> 6] = esum;
  __syncthreads();
  float total = red[0] + red[1] + red[2] + red[3] + (float)(4096 - na) * __expf(0.f - mx);
  float inv = 1.f / total;
  _Float16* Ap = Asub + ((size_t)blk << 10);
#pragma unroll
  for (int s4 = 0; s4 < 4; ++s4) Ap[s4 * 256 + tid] = (_Float16)(e[s4] * inv);
}

// ---------------- K4: G = Asub * Rts^T, BK=64 + swizzle, K trimmed to ceil(na/64)*64.
// Slots >= na have Asub exactly 0 (e=0 stored), so skipped MFMA contribute +0 exactly:
// bit-identical acc. Atomic scatter into y. --------------------------------------------
__global__ __launch_bounds__(256) void k_gemm_recon(const _Float16* __restrict__ Asub,
                                                    const _Float16* __restrict__ Rts,
                                                    const int* __restrict__ nAct,
                                                    float* __restrict__ y) {
  int b = blockIdx.z;
  const _Float16* Ab = Asub + ((size_t)b << 22);
  const _Float16* Bb = Rts + (size_t)b * 640 * 1024;
  int kMax = ((nAct[b] + 63) >> 6) << 6;
  int rowBase = blockIdx.y * 128, colBase = blockIdx.x * 128;  // col over 640
  __shared__ alignas(16) _Float16 As[128 * 64];
  __shared__ alignas(16) _Float16 Bs[128 * 64];
  int tid = threadIdx.x, wave = tid >> 6, lane = tid & 63;
  int q = lane >> 4, rr = lane & 15;
  int wr = (wave >> 1) * 64, wc = (wave & 1) * 64;
  f32x4 acc[4][4] = {};
  for (int kt = 0; kt < kMax; kt += 64) {
    __syncthreads();
#pragma unroll
    for (int t = 0; t < 4; ++t) {
      int chunk = t * 256 + wave * 64 + lane;
      int row = chunk >> 3;
      int kc = ((chunk & 7) ^ (row & 7)) * 8;
      gload_lds16(Ab + ((size_t)(rowBase + row) << 10) + kt + kc,
                  As + (size_t)(t * 256 + wave * 64) * 8);
      gload_lds16(Bb + ((size_t)(colBase + row) << 10) + kt + kc,
                  Bs + (size_t)(t * 256 + wave * 64) * 8);
    }
    __syncthreads();
#pragma unroll
    for (int ks = 0; ks < 2; ++ks) {
      f16x8 af[4], bf[4];
#pragma unroll
      for (int mi = 0; mi < 4; ++mi) {
        int r = wr + mi * 16 + rr;
        int ps = (ks * 4 + q) ^ (r & 7);
        af[mi] = *(const f16x8*)(As + r * 64 + ps * 8);
      }
#pragma unroll
      for (int ni = 0; ni < 4; ++ni) {
        int r = wc + ni * 16 + rr;
        int ps = (ks * 4 + q) ^ (r & 7);
        bf[ni] = *(const f16x8*)(Bs + r * 64 + ps * 8);
      }
#pragma unroll
      for (int mi = 0; mi < 4; ++mi)
#pragma unroll
        for (int ni = 0; ni < 4; ++ni)
          acc[mi][ni] = __builtin_amdgcn_mfma_f32_16x16x32_f16(af[mi], bf[ni], acc[mi][ni], 0, 0, 0);
    }
  }
#pragma unroll
  for (int ni = 0; ni < 4; ++ni) {
    int gc = colBase + wc + ni * 16 + rr;
    if (gc < 576) {
      int kk = gc >> 6, c = gc & 63;
      int kh = kk / 3, kw = kk - kh * 3;
#pragma unroll
      for (int mi = 0; mi < 4; ++mi)
#pragma unroll
        for (int reg = 0; reg < 4; ++reg) {
          int gp = rowBase + wr + mi * 16 + q * 4 + reg;
          int i = gp >> 6, j = gp & 63;
          int u = 2 * i + kh, v = 2 * j + kw;
          if (u < 128 && v < 128)
            atomicAdd(y + (((size_t)((b * 128 + u) * 128 + v)) << 6) + c,
                      0.25f * acc[mi][ni][reg]);
        }
    }
  }
}

extern "C" void kernel_launch(void* const* d_in, const int* in_sizes, int n_in,
                              void* d_out, int out_size, void* d_ws, size_t ws_size,
                              hipStream_t stream) {
  const float* x = (const float*)d_in[0];
  const float* mask = (const float*)d_in[1];
  float* out = (float*)d_out;
  float* y = out;                 // [2][128][128][64]
  float* att = out + 2097152;     // [2][4096][4096]

  char* ws = (char*)d_ws;
  _Float16* f_h = (_Float16*)(ws + 0);            //  1,048,576 B
  float* sumsq = (float*)(ws + 0x100000);         //     32,768
  float* mlow = (float*)(ws + 0x108000);          //     32,768
  float* invn = (float*)(ws + 0x110000);          //     32,768
  _Float16* P = (_Float16*)(ws + 0x120000);       //  9,437,184
  _Float16* Rt = (_Float16*)(ws + 0xA20000);      // 10,485,760  [2][640][4096]
  int* actIdx = (int*)(ws + 0x1420000);           //      8,192  [2][1024]
  int* nAct = (int*)(ws + 0x1422000);             //          8
  _Float16* Rts = (_Float16*)(ws + 0x1430000);    //  2,621,440  [2][640][1024]
  _Float16* Asub = (_Float16*)(ws + 0x16B0000);   // 16,777,216  [2][4096][1024]
  (void)in_sizes; (void)n_in; (void)out_size; (void)ws_size;

  k_prt<<<2944, 256, 0, stream>>>(x, mask, f_h, sumsq, mlow, Rt, y);
  k_norm_compact<<<2, 1024, 0, stream>>>(sumsq, mlow, invn, actIdx, nAct);
  k_psub<<<3328, 256, 0, stream>>>(f_h, P, Rt, actIdx, Rts);
  k_gemm_sim<<<dim3(528, 1, 2), 256, 0, stream>>>(P, invn, att);
  k_fuse_softmax3<<<8192, 256, 0, stream>>>(att, actIdx, nAct, Asub);
  k_gemm_recon<<<dim3(5, 32, 2), 256, 0, stream>>>(Asub, Rts, nAct, y);
}

// Round 12
// 285.399 us; speedup vs baseline: 1.3809x; 1.0302x over previous
//
#include <hip/hip_runtime.h>
#include <hip/hip_bf16.h>

typedef _Float16 f16x8 __attribute__((ext_vector_type(8)));
typedef float f32x4 __attribute__((ext_vector_type(4)));

__device__ __forceinline__ void gload_lds16(const void* gptr, void* lptr) {
  __builtin_amdgcn_global_load_lds(
      (const __attribute__((address_space(1))) void*)gptr,
      (__attribute__((address_space(3))) void*)lptr, 16, 0, 0);
}

// ---------------- K1a + y-zero merged ----------------
// blocks [0,2048): k_pre body (4 waves, one (b,i,j) site per wave)
// blocks [2048,2560): zero y (replaces hipMemsetAsync dispatch)
__global__ __launch_bounds__(256) void k_prt(const float* __restrict__ x,
                                             const float* __restrict__ mask,
                                             _Float16* __restrict__ f_h,
                                             float* __restrict__ sumsq,
                                             float* __restrict__ mlow,
                                             float* __restrict__ y) {
  if (blockIdx.x < 2048) {
    int wave = threadIdx.x >> 6, c = threadIdx.x & 63;
    int blk = blockIdx.x * 4 + wave;   // b*4096 + i*64 + j
    int b = blk >> 12, ij = blk & 4095;
    int i = ij >> 6, j = ij & 63;
    size_t base = ((size_t)(b * 128 + 2 * i) * 128 + 2 * j) * 64 + c;
    float f = 0.25f * (x[base] + x[base + 64] + x[base + 128 * 64] + x[base + 128 * 64 + 64]);
    f_h[(size_t)blk * 64 + c] = (_Float16)f;
    float fsq = f * f;
    for (int off = 32; off; off >>= 1) fsq += __shfl_down(fsq, off);
    if (c == 0) {
      sumsq[blk] = fsq;
      size_t mb = (size_t)(b * 128 + 2 * i) * 128 + 2 * j;
      mlow[blk] = 0.25f * (mask[mb] + mask[mb + 1] + mask[mb + 128] + mask[mb + 129]);
    }
    return;
  }
  int idx = blockIdx.x - 2048;         // [0,512): 2,097,152 floats / 512 = 1024 f32x4
  f32x4* Y4 = (f32x4*)y;
  f32x4 z = {0.f, 0.f, 0.f, 0.f};
#pragma unroll
  for (int k = 0; k < 4; ++k) Y4[idx * 1024 + k * 256 + threadIdx.x] = z;
}

// ---------------- K1d: mm flags (LDS) + deterministic compaction (invn moved out) -----
__global__ __launch_bounds__(1024) void k_norm_compact(const float* __restrict__ mlow,
                                                       int* __restrict__ actIdx,
                                                       int* __restrict__ nAct) {
  int b = blockIdx.x;
  int t = threadIdx.x;  // 1024
  __shared__ unsigned char mmf[4096];
  for (int l = t; l < 4096; l += 1024) {
    int li = l >> 6, lj = l & 63;
    bool ok = true;
    for (int dh = -1; dh <= 1; ++dh)
      for (int dw = -1; dw <= 1; ++dw) {
        int ii = li + dh, jj = lj + dw;
        float mv = 0.f;
        if ((unsigned)ii < 64u && (unsigned)jj < 64u) mv = mlow[(b << 12) + ii * 64 + jj];
        ok = ok && (mv == 1.0f);   // exact-1.0 patch <=> all 9 entries exactly 1.0
      }
    mmf[l] = ok ? 1 : 0;
  }
  __syncthreads();
  int lane = t & 63, wv = t >> 6;  // 16 waves
  __shared__ int wsum[16];
  __shared__ int sbase;
  if (t == 0) sbase = 0;
  __syncthreads();
  for (int chunk = 0; chunk < 4; ++chunk) {
    int l = chunk * 1024 + t;
    int flag = mmf[l] ? 1 : 0;
    unsigned long long m = __ballot(flag);
    int wpre = __popcll(m & ((1ull << lane) - 1ull));
    if (lane == 0) wsum[wv] = __popcll(m);
    __syncthreads();
    int off = sbase;
    for (int w2 = 0; w2 < wv; ++w2) off += wsum[w2];
    if (flag) {
      int pos = off + wpre;
      if (pos < 1024) actIdx[(b << 10) + pos] = l;
    }
    __syncthreads();
    if (t == 0) {
      int s2 = 0;
      for (int w2 = 0; w2 < 16; ++w2) s2 += wsum[w2];
      sbase += s2;
    }
    __syncthreads();
  }
  int total = sbase;
  if (t >= total) actIdx[(b << 10) + t] = 0;  // safe index; weight will be 0
  if (t == 0) nAct[b] = (total > 1024) ? 1024 : total;
}

// ---------------- K1p + direct-Rts + invn merged --------------------------------------
// blocks [0,2048): build_p (4 waves/block)
// blocks [2048,3200): Rts[b][n][s] gathered DIRECTLY from x (Rt intermediate removed:
//   Rts[b][n][s] = Rt[b][n][aIdx[s]] composes to x[b][2li+kh][2lj+kw][c] with bounds->0;
//   identical f32->f16 conversion, bit-identical values). Pad rows n in [576,640) stay
//   unwritten (poison) — only feed recon acc columns gc>=576 (discarded), as before.
// blocks [3200,3232): invn[l] from sumsq 3x3 stencil (old k_norm_mm math, bit-identical)
__global__ __launch_bounds__(256) void k_psub(const _Float16* __restrict__ f_h,
                                              _Float16* __restrict__ P,
                                              const float* __restrict__ x,
                                              const int* __restrict__ actIdx,
                                              _Float16* __restrict__ Rts,
                                              const float* __restrict__ sumsq,
                                              float* __restrict__ invn) {
  if (blockIdx.x < 2048) {
    int wave = threadIdx.x >> 6, c = threadIdx.x & 63;
    int blk = blockIdx.x * 4 + wave;  // b*4096+l
    int b = blk >> 12, l = blk & 4095;
    int li = l >> 6, lj = l & 63;
    _Float16* dst = P + (size_t)blk * 576 + c;
#pragma unroll
    for (int kk = 0; kk < 9; ++kk) {
      int kh = kk / 3, kw = kk % 3;
      int ii = li + kh - 1, jj = lj + kw - 1;
      _Float16 v = (_Float16)0.f;
      if ((unsigned)ii < 64u && (unsigned)jj < 64u)
        v = f_h[((size_t)(b << 12) + ii * 64 + jj) * 64 + c];
      dst[kk * 64] = v;
    }
    return;
  }
  if (blockIdx.x >= 3200) {
    int t = (blockIdx.x - 3200) * 256 + threadIdx.x;  // [0,8192)
    int b = t >> 12, l = t & 4095;
    int li = l >> 6, lj = l & 63;
    float s = 0.f;
    for (int dh = -1; dh <= 1; ++dh)
      for (int dw = -1; dw <= 1; ++dw) {
        int ii = li + dh, jj = lj + dw;
        if ((unsigned)ii < 64u && (unsigned)jj < 64u) s += sumsq[(b << 12) + ii * 64 + jj];
      }
    invn[t] = 1.0f / fmaxf(sqrtf(s), 1e-4f);
    return;
  }
  int idx = blockIdx.x - 2048;        // [0,1152) = 576 * 2
  int n = idx % 576, b = idx / 576;
  int kk = n >> 6, c = n & 63;
  int kh = kk / 3, kw = kk - kh * 3;
  _Float16* dst = Rts + ((size_t)(b * 640 + n) << 10);
  const int* aIdx = actIdx + (b << 10);
  const float* xb = x + ((size_t)b << 20);  // b*128*128*64
  int s0 = threadIdx.x * 4;           // 256 threads x 4 = 1024 slots
  unsigned long long v = 0;
#pragma unroll
  for (int u4 = 0; u4 < 4; ++u4) {
    int l = aIdx[s0 + u4];
    int li = l >> 6, lj = l & 63;
    int r = 2 * li + kh, vv = 2 * lj + kw;
    float val = (r < 128 && vv < 128) ? xb[((size_t)(r * 128 + vv) << 6) + c] : 0.f;
    _Float16 h = (_Float16)val;
    v |= ((unsigned long long)*(unsigned short*)&h) << (16 * u4);
  }
  *(unsigned long long*)(dst + s0) = v;
}

// ---------------- K2: symmetric GEMM, BK=64 + XOR slot-swizzle + XCD idx swizzle.
// Plain (cache-combined) stores: R10 proved nontemporal att stores cause ~1.7x HBM
// write amplification (WRITE_SIZE 230MB vs 134MB logical) — L2 is the write combiner. --
__global__ __launch_bounds__(256) void k_gemm_sim(const _Float16* __restrict__ P,
                                                  const float* __restrict__ invn,
                                                  float* __restrict__ att) {
  int b = blockIdx.z;
  const _Float16* Ab = P + (size_t)b * 4096 * 576;
  int idx0 = blockIdx.x;              // 528 = 8 * 66, bijective XCD-contiguous swizzle
  int idx = (idx0 & 7) * 66 + (idx0 >> 3);
  int bj = (int)((sqrtf(8.f * (float)idx + 1.f) - 1.f) * 0.5f);
  while ((bj + 1) * (bj + 2) / 2 <= idx) ++bj;
  while (bj * (bj + 1) / 2 > idx) --bj;
  int bi = idx - bj * (bj + 1) / 2;
  int rowBase = bi * 128, colBase = bj * 128;
  bool diag = (bi == bj);

  __shared__ alignas(16) _Float16 As[128 * 64];
  __shared__ alignas(16) _Float16 Bs[128 * 64];
  __shared__ alignas(16) float tbuf[32][132];
  int tid = threadIdx.x, wave = tid >> 6, lane = tid & 63;
  int q = lane >> 4, rr = lane & 15;
  int wr = (wave >> 1) * 64, wc = (wave & 1) * 64;
  f32x4 acc[4][4] = {};
  for (int kt = 0; kt < 576; kt += 64) {
    __syncthreads();
#pragma unroll
    for (int t = 0; t < 4; ++t) {
      int chunk = t * 256 + wave * 64 + lane;  // 1024 chunks of 16B per tile
      int row = chunk >> 3;
      int kc = ((chunk & 7) ^ (row & 7)) * 8;  // pre-swizzled source slot
      gload_lds16(Ab + (size_t)(rowBase + row) * 576 + kt + kc,
                  As + (size_t)(t * 256 + wave * 64) * 8);
      if (!diag)
        gload_lds16(Ab + (size_t)(colBase + row) * 576 + kt + kc,
                    Bs + (size_t)(t * 256 + wave * 64) * 8);
    }
    __syncthreads();
    const _Float16* Bsrc = diag ? As : Bs;
#pragma unroll
    for (int ks = 0; ks < 2; ++ks) {
      f16x8 af[4], bf[4];
#pragma unroll
      for (int mi = 0; mi < 4; ++mi) {
        int r = wr + mi * 16 + rr;
        int ps = (ks * 4 + q) ^ (r & 7);
        af[mi] = *(const f16x8*)(As + r * 64 + ps * 8);
      }
#pragma unroll
      for (int ni = 0; ni < 4; ++ni) {
        int r = wc + ni * 16 + rr;
        int ps = (ks * 4 + q) ^ (r & 7);
        bf[ni] = *(const f16x8*)(Bsrc + r * 64 + ps * 8);
      }
#pragma unroll
      for (int mi = 0; mi < 4; ++mi)
#pragma unroll
        for (int ni = 0; ni < 4; ++ni)
          acc[mi][ni] = __builtin_amdgcn_mfma_f32_16x16x32_f16(af[mi], bf[ni], acc[mi][ni], 0, 0, 0);
    }
  }
  float* attb = att + ((size_t)b << 24);
#pragma unroll
  for (int ni = 0; ni < 4; ++ni) {
    int gc = colBase + wc + ni * 16 + rr;
    float sc = invn[(b << 12) + gc];
#pragma unroll
    for (int mi = 0; mi < 4; ++mi)
#pragma unroll
      for (int reg = 0; reg < 4; ++reg) {
        int gr = rowBase + wr + mi * 16 + q * 4 + reg;
        attb[((size_t)gr << 12) + gc] = acc[mi][ni][reg] * sc;
      }
  }
  if (diag) return;
  const float* ivrow = invn + (b << 12) + rowBase;
#pragma unroll
  for (int ph = 0; ph < 4; ++ph) {
    __syncthreads();
    if ((ph >> 1) == (wc >> 6)) {
      int nlo = (ph & 1) * 2;
#pragma unroll
      for (int nn = 0; nn < 2; ++nn) {
        int ni = nlo + nn;
        int rloc = nn * 16 + rr;
#pragma unroll
        for (int mi = 0; mi < 4; ++mi)
          *(f32x4*)&tbuf[rloc][wr + mi * 16 + q * 4] = acc[mi][ni];
      }
    }
    __syncthreads();
    int r = tid >> 3;
    int cbase = (tid & 7) * 16;
    int grow = colBase + ph * 32 + r;
    float* dst = attb + ((size_t)grow << 12) + rowBase + cbase;
#pragma unroll
    for (int cc = 0; cc < 16; cc += 4) {
      f32x4 v = *(f32x4*)&tbuf[r][cbase + cc];
      f32x4 s = *(const f32x4*)(ivrow + cbase + cc);
      *(f32x4*)(dst + cc) = v * s;
    }
  }
}

// ---------------- K3: fuse (9-pt diagonal stencil) + masked softmax, active cols only.
// 8192 blocks, one p each (max TLP — measured optimum; fuse5/fuse6 reuse variants both
// regressed: the kernel is latency-bound, not traffic-bound). --------------------------
__global__ __launch_bounds__(256) void k_fuse_softmax3(const float* __restrict__ att,
                                                       const int* __restrict__ actIdx,
                                                       const int* __restrict__ nAct,
                                                       _Float16* __restrict__ Asub) {
  int blk0 = blockIdx.x;                    // XCD-contiguous swizzle: 8192 = 8 * 1024
  int blk = (blk0 & 7) * 1024 + (blk0 >> 3);
  int b = blk >> 12, p = blk & 4095;
  const float* Y = att + ((size_t)b << 24);
  const int* aIdx = actIdx + (b << 10);
  int na = nAct[b];
  int tid = threadIdx.x;
  int pi = p >> 6, pj = p & 63;
  int acol = pj * 64 + pi;                  // col-major flat index of p

  int ls[4];
  bool act[4];
  float F[4] = {0.f, 0.f, 0.f, 0.f};
#pragma unroll
  for (int s4 = 0; s4 < 4; ++s4) {
    int slot = s4 * 256 + tid;
    ls[s4] = aIdx[slot];                    // safe 0 for padded slots
    act[s4] = (slot < na);
  }

#pragma unroll
  for (int d2 = -1; d2 <= 1; ++d2) {
    int a2 = acol + d2;
    if ((unsigned)a2 >= 4096u) continue;    // wave-uniform branch
    int p2 = ((a2 & 63) << 6) | (a2 >> 6);
    int l2[4];
    bool lok[4];
#pragma unroll
    for (int s4 = 0; s4 < 4; ++s4) {
      int l = ls[s4];
      int bcol = ((l & 63) << 6) | (l >> 6);
      int b2 = bcol + d2;
      lok[s4] = act[s4] && ((unsigned)b2 < 4096u);
      int b2c = lok[s4] ? b2 : 0;
      l2[s4] = ((b2c & 63) << 6) | (b2c >> 6);  // consecutive across lanes in active runs
    }
#pragma unroll
    for (int d1 = -1; d1 <= 1; ++d1) {
      int qq = p2 + d1;
      if ((unsigned)qq >= 4096u) continue;  // wave-uniform branch
      const float* row = Y + ((size_t)qq << 12);
#pragma unroll
      for (int s4 = 0; s4 < 4; ++s4) {
        int rr2 = l2[s4] + d1;
        if (lok[s4] && (unsigned)rr2 < 4096u) F[s4] += row[rr2];
      }
    }
  }

  float z[4];
  float mx = (na < 4096) ? 0.f : -1e30f;    // masked columns contribute logit 0
#pragma unroll
  for (int s4 = 0; s4 < 4; ++s4) {
    z[s4] = act[s4] ? F[s4] * 10.f : -1e30f;
    mx = fmaxf(mx, z[s4]);
  }
  __shared__ float red[4];
  for (int off = 32; off; off >>= 1) mx = fmaxf(mx, __shfl_down(mx, off));
  if ((tid & 63) == 0) red[tid >> 6] = mx;
  __syncthreads();
  mx = fmaxf(fmaxf(red[0], red[1]), fmaxf(red[2], red[3]));
  float e[4];
  float esum = 0.f;
#pragma unroll
  for (int s4 = 0; s4 < 4; ++s4) {
    e[s4] = act[s4] ? __expf(z[s4] - mx) : 0.f;
    esum += e[s4];
  }
  for (int off = 32; off; off >>= 1) esum += __shfl_down(esum, off);
  __syncthreads();
  if ((tid & 63) == 0) red[tid >> 6] = esum;
  __syncthreads();
  float total = red[0] + red[1] + red[2] + red[3] + (float)(4096 - na) * __expf(0.f - mx);
  float inv = 1.f / total;
  _Float16* Ap = Asub + ((size_t)blk << 10);
#pragma unroll
  for (int s4 = 0; s4 < 4; ++s4) Ap[s4 * 256 + tid] = (_Float16)(e[s4] * inv);
}

// ---------------- K4: G = Asub * Rts^T, BK=64 + swizzle, K trimmed to ceil(na/64)*64.
// Slots >= na have Asub exactly 0 (e=0 stored), so skipped MFMA contribute +0 exactly:
// bit-identical acc. Atomic scatter into y. --------------------------------------------
__global__ __launch_bounds__(256) void k_gemm_recon(const _Float16* __restrict__ Asub,
                                                    const _Float16* __restrict__ Rts,
                                                    const int* __restrict__ nAct,
                                                    float* __restrict__ y) {
  int b = blockIdx.z;
  const _Float16* Ab = Asub + ((size_t)b << 22);
  const _Float16* Bb = Rts + (size_t)b * 640 * 1024;
  int kMax = ((nAct[b] + 63) >> 6) << 6;
  int rowBase = blockIdx.y * 128, colBase = blockIdx.x * 128;  // col over 640
  __shared__ alignas(16) _Float16 As[128 * 64];
  __shared__ alignas(16) _Float16 Bs[128 * 64];
  int tid = threadIdx.x, wave = tid >> 6, lane = tid & 63;
  int q = lane >> 4, rr = lane & 15;
  int wr = (wave >> 1) * 64, wc = (wave & 1) * 64;
  f32x4 acc[4][4] = {};
  for (int kt = 0; kt < kMax; kt += 64) {
    __syncthreads();
#pragma unroll
    for (int t = 0; t < 4; ++t) {
      int chunk = t * 256 + wave * 64 + lane;
      int row = chunk >> 3;
      int kc = ((chunk & 7) ^ (row & 7)) * 8;
      gload_lds16(Ab + ((size_t)(rowBase + row) << 10) + kt + kc,
                  As + (size_t)(t * 256 + wave * 64) * 8);
      gload_lds16(Bb + ((size_t)(colBase + row) << 10) + kt + kc,
                  Bs + (size_t)(t * 256 + wave * 64) * 8);
    }
    __syncthreads();
#pragma unroll
    for (int ks = 0; ks < 2; ++ks) {
      f16x8 af[4], bf[4];
#pragma unroll
      for (int mi = 0; mi < 4; ++mi) {
        int r = wr + mi * 16 + rr;
        int ps = (ks * 4 + q) ^ (r & 7);
        af[mi] = *(const f16x8*)(As + r * 64 + ps * 8);
      }
#pragma unroll
      for (int ni = 0; ni < 4; ++ni) {
        int r = wc + ni * 16 + rr;
        int ps = (ks * 4 + q) ^ (r & 7);
        bf[ni] = *(const f16x8*)(Bs + r * 64 + ps * 8);
      }
#pragma unroll
      for (int mi = 0; mi < 4; ++mi)
#pragma unroll
        for (int ni = 0; ni < 4; ++ni)
          acc[mi][ni] = __builtin_amdgcn_mfma_f32_16x16x32_f16(af[mi], bf[ni], acc[mi][ni], 0, 0, 0);
    }
  }
#pragma unroll
  for (int ni = 0; ni < 4; ++ni) {
    int gc = colBase + wc + ni * 16 + rr;
    if (gc < 576) {
      int kk = gc >> 6, c = gc & 63;
      int kh = kk / 3, kw = kk - kh * 3;
#pragma unroll
      for (int mi = 0; mi < 4; ++mi)
#pragma unroll
        for (int reg = 0; reg < 4; ++reg) {
          int gp = rowBase + wr + mi * 16 + q * 4 + reg;
          int i = gp >> 6, j = gp & 63;
          int u = 2 * i + kh, v = 2 * j + kw;
          if (u < 128 && v < 128)
            atomicAdd(y + (((size_t)((b * 128 + u) * 128 + v)) << 6) + c,
                      0.25f * acc[mi][ni][reg]);
        }
    }
  }
}

extern "C" void kernel_launch(void* const* d_in, const int* in_sizes, int n_in,
                              void* d_out, int out_size, void* d_ws, size_t ws_size,
                              hipStream_t stream) {
  const float* x = (const float*)d_in[0];
  const float* mask = (const float*)d_in[1];
  float* out = (float*)d_out;
  float* y = out;                 // [2][128][128][64]
  float* att = out + 2097152;     // [2][4096][4096]

  char* ws = (char*)d_ws;
  _Float16* f_h = (_Float16*)(ws + 0);            //  1,048,576 B
  float* sumsq = (float*)(ws + 0x100000);         //     32,768
  float* mlow = (float*)(ws + 0x108000);          //     32,768
  float* invn = (float*)(ws + 0x110000);          //     32,768
  _Float16* P = (_Float16*)(ws + 0x120000);       //  9,437,184
  int* actIdx = (int*)(ws + 0x1420000);           //      8,192  [2][1024]
  int* nAct = (int*)(ws + 0x1422000);             //          8
  _Float16* Rts = (_Float16*)(ws + 0x1430000);    //  2,621,440  [2][640][1024]
  _Float16* Asub = (_Float16*)(ws + 0x16B0000);   // 16,777,216  [2][4096][1024]
  (void)in_sizes; (void)n_in; (void)out_size; (void)ws_size;

  k_prt<<<2560, 256, 0, stream>>>(x, mask, f_h, sumsq, mlow, y);
  k_norm_compact<<<2, 1024, 0, stream>>>(mlow, actIdx, nAct);
  k_psub<<<3232, 256, 0, stream>>>(f_h, P, x, actIdx, Rts, sumsq, invn);
  k_gemm_sim<<<dim3(528, 1, 2), 256, 0, stream>>>(P, invn, att);
  k_fuse_softmax3<<<8192, 256, 0, stream>>>(att, actIdx, nAct, Asub);
  k_gemm_recon<<<dim3(5, 32, 2), 256, 0, stream>>>(Asub, Rts, nAct, y);
}